// Round 8
// baseline (71.366 us; speedup 1.0000x reference)
//
#include <hip/hip_runtime.h>
#include <math.h>

#define TPB 256

constexpr int Bn    = 131072;
constexpr float LOG2E = 1.4426950408889634f;

typedef float v2f __attribute__((ext_vector_type(2)));

__global__ __launch_bounds__(TPB, 4)
void gat_ppo_kernel(const float* __restrict__ xg,
                    const float* __restrict__ adjg,
                    const float* __restrict__ Wg,
                    const float* __restrict__ ahg,
                    const float* __restrict__ wog,
                    const float* __restrict__ aog,
                    const float* __restrict__ muWg,
                    const float* __restrict__ mubg,
                    const float* __restrict__ sgWg,
                    const float* __restrict__ sgbg,
                    const float* __restrict__ vWg,
                    const float* __restrict__ vbg,
                    float* __restrict__ outg)
{
    // Two independent graph-rows per thread (q = 0,1), interleaved at
    // instruction level for 2x ILP. Per wave: 2 Wh tiles (8 graphs x 25
    // float4 each). Block: 4 waves x 2 x 200 float4 = 25.6 KB LDS.
    __shared__ float4 tile[4 * 2 * 200];

    const int lb = threadIdx.x;
    const int w  = lb >> 6;                 // wave id in block
    const int g  = (lb & 63) >> 3;          // graph within wave (per tile)
    const int n  = lb & 7;                  // node id
    const size_t rbase = (size_t)blockIdx.x * (2 * TPB) + lb;

    float4* wtA = tile + w * 400;
    float4* wtB = wtA + 200;

    // ---- adj -> mask and x -> regs for both rows (independent chains) ----
    unsigned amask[2];
    float x[2][30];
    #pragma unroll
    for (int q = 0; q < 2; ++q) {
        const size_t r = rbase + q * TPB;
        const float4* a4 = (const float4*)(adjg) + r * 2;
        float4 a0 = a4[0], a1 = a4[1];
        amask[q] =  (unsigned)(a0.x > 0.0f)
                 | ((unsigned)(a0.y > 0.0f) << 1)
                 | ((unsigned)(a0.z > 0.0f) << 2)
                 | ((unsigned)(a0.w > 0.0f) << 3)
                 | ((unsigned)(a1.x > 0.0f) << 4)
                 | ((unsigned)(a1.y > 0.0f) << 5)
                 | ((unsigned)(a1.z > 0.0f) << 6)
                 | ((unsigned)(a1.w > 0.0f) << 7);
        const float2* xr = (const float2*)(xg + r * 30);
        #pragma unroll
        for (int k = 0; k < 15; ++k) {
            float2 v = xr[k];
            x[q][2 * k] = v.x; x[q][2 * k + 1] = v.y;
        }
    }

    // ---- per-head: Wh (both rows, shared W operand) -> tiles -> softmax -> agg ----
    const v2f* Wp = (const v2f*)Wg;
    float wh2[2] = {0.0f, 0.0f};

    #pragma unroll
    for (int h = 0; h < 3; ++h) {
        v2f acc[2][4];
        #pragma unroll
        for (int q = 0; q < 2; ++q)
            #pragma unroll
            for (int o2 = 0; o2 < 4; ++o2) acc[q][o2] = (v2f){0.0f, 0.0f};

        #pragma unroll
        for (int f = 0; f < 30; ++f) {
            #pragma unroll
            for (int o2 = 0; o2 < 4; ++o2) {
                v2f wv = Wp[h * 120 + f * 4 + o2];   // one s_load feeds both rows
                acc[0][o2] = __builtin_elementwise_fma((v2f){x[0][f], x[0][f]}, wv, acc[0][o2]);
                acc[1][o2] = __builtin_elementwise_fma((v2f){x[1][f], x[1][f]}, wv, acc[1][o2]);
            }
        }

        // scores (log2 domain) for both rows
        float f1h[2], f2h[2];
        #pragma unroll
        for (int q = 0; q < 2; ++q) {
            float s1 = 0.0f, s2 = 0.0f;
            #pragma unroll
            for (int o2 = 0; o2 < 4; ++o2) {
                s1 = fmaf(acc[q][o2].x, ahg[h * 16 + 2 * o2],     s1);
                s1 = fmaf(acc[q][o2].y, ahg[h * 16 + 2 * o2 + 1], s1);
                s2 = fmaf(acc[q][o2].x, ahg[h * 16 + 8 + 2 * o2],     s2);
                s2 = fmaf(acc[q][o2].y, ahg[h * 16 + 8 + 2 * o2 + 1], s2);
            }
            f1h[q] = s1 * LOG2E;
            f2h[q] = s2 * LOG2E;
        }

        // publish Wh rows to the two wave-local tiles
        wtA[g * 25 + n * 3]     = (float4){acc[0][0].x, acc[0][0].y, acc[0][1].x, acc[0][1].y};
        wtA[g * 25 + n * 3 + 1] = (float4){acc[0][2].x, acc[0][2].y, acc[0][3].x, acc[0][3].y};
        wtB[g * 25 + n * 3]     = (float4){acc[1][0].x, acc[1][0].y, acc[1][1].x, acc[1][1].y};
        wtB[g * 25 + n * 3 + 1] = (float4){acc[1][2].x, acc[1][2].y, acc[1][3].x, acc[1][3].y};

        // masked softmax weights (unnormalized, exp2), chains interleaved
        float p[2][8];
        float s[2] = {0.0f, 0.0f};
        #pragma unroll
        for (int m = 0; m < 8; ++m) {
            #pragma unroll
            for (int q = 0; q < 2; ++q) {
                float ev = f1h[q] + __shfl(f2h[q], m, 8);
                ev = fmaxf(ev, 0.2f * ev);                 // leaky (log2-scaled)
                float pe = ((amask[q] >> m) & 1u) ? __builtin_amdgcn_exp2f(ev) : 0.0f;
                p[q][m] = pe; s[q] += pe;
            }
        }

        // aggregate unnormalized (broadcast tile reads), interleaved
        v2f hacc[2][4];
        #pragma unroll
        for (int q = 0; q < 2; ++q)
            #pragma unroll
            for (int o2 = 0; o2 < 4; ++o2) hacc[q][o2] = (v2f){0.0f, 0.0f};

        #pragma unroll
        for (int m = 0; m < 8; ++m) {
            float4 loA = wtA[g * 25 + m * 3];
            float4 hiA = wtA[g * 25 + m * 3 + 1];
            float4 loB = wtB[g * 25 + m * 3];
            float4 hiB = wtB[g * 25 + m * 3 + 1];
            v2f avA = (v2f){p[0][m], p[0][m]};
            v2f avB = (v2f){p[1][m], p[1][m]};
            hacc[0][0] = __builtin_elementwise_fma(avA, (v2f){loA.x, loA.y}, hacc[0][0]);
            hacc[0][1] = __builtin_elementwise_fma(avA, (v2f){loA.z, loA.w}, hacc[0][1]);
            hacc[0][2] = __builtin_elementwise_fma(avA, (v2f){hiA.x, hiA.y}, hacc[0][2]);
            hacc[0][3] = __builtin_elementwise_fma(avA, (v2f){hiA.z, hiA.w}, hacc[0][3]);
            hacc[1][0] = __builtin_elementwise_fma(avB, (v2f){loB.x, loB.y}, hacc[1][0]);
            hacc[1][1] = __builtin_elementwise_fma(avB, (v2f){loB.z, loB.w}, hacc[1][1]);
            hacc[1][2] = __builtin_elementwise_fma(avB, (v2f){hiB.x, hiB.y}, hacc[1][2]);
            hacc[1][3] = __builtin_elementwise_fma(avB, (v2f){hiB.z, hiB.w}, hacc[1][3]);
        }

        #pragma unroll
        for (int q = 0; q < 2; ++q) {
            float rs = 1.0f / s[q];
            #pragma unroll
            for (int o2 = 0; o2 < 4; ++o2) {
                #pragma unroll
                for (int j = 0; j < 2; ++j) {
                    float hv = hacc[q][o2][j] * rs;
                    hv = (hv > 0.0f) ? hv : (__expf(hv) - 1.0f);       // elu
                    wh2[q] = fmaf(hv, wog[h * 8 + 2 * o2 + j], wh2[q]); // h @ W_out
                }
            }
        }
    }

    // ---- second GAT layer (log2 domain, deferred norm), both rows ----
    const float a0c = aog[0] * LOG2E, a1c = aog[1] * LOG2E;
    float g2v[2];
    #pragma unroll
    for (int q = 0; q < 2; ++q) {
        float wh2a[8];
        #pragma unroll
        for (int m = 0; m < 8; ++m) wh2a[m] = __shfl(wh2[q], m, 8);

        float g1 = a0c * wh2[q];
        float s2s = 0.0f, og = 0.0f;
        #pragma unroll
        for (int m = 0; m < 8; ++m) {
            float ev = fmaf(a1c, wh2a[m], g1);
            ev = fmaxf(ev, 0.2f * ev);
            float pe = ((amask[q] >> m) & 1u) ? __builtin_amdgcn_exp2f(ev) : 0.0f;
            s2s += pe;
            og = fmaf(pe, wh2a[m], og);
        }
        og /= s2s;
        g2v[q] = (og > 0.0f) ? og : (__expf(og) - 1.0f);   // elu -> g[b][n]
    }

    // ---- MLP heads for both rows ----
    const v2f* muWp = (const v2f*)muWg;
    const v2f* sgWp = (const v2f*)sgWg;
    const v2f* vWp  = (const v2f*)vWg;
    #pragma unroll
    for (int q = 0; q < 2; ++q) {
        v2f gp[4];
        #pragma unroll
        for (int m = 0; m < 4; ++m)
            gp[m] = (v2f){__shfl(g2v[q], 2 * m, 8), __shfl(g2v[q], 2 * m + 1, 8)};

        v2f ma = (v2f){0.0f, 0.0f}, sa = (v2f){0.0f, 0.0f}, va = (v2f){0.0f, 0.0f};
        #pragma unroll
        for (int k = 0; k < 4; ++k) {
            ma = __builtin_elementwise_fma(gp[k], muWp[n * 4 + k], ma);
            sa = __builtin_elementwise_fma(gp[k], sgWp[n * 4 + k], sa);
            va = __builtin_elementwise_fma(gp[k], vWp[k],          va);
        }
        float mu = ma.x + ma.y + mubg[n];
        float sg = sa.x + sa.y + sgbg[n];
        float vv = va.x + va.y + vbg[0];

        mu = 1.0f / (1.0f + __expf(-mu));                               // sigmoid
        sg = fmaxf(sg, 0.0f) + log1pf(__expf(-fabsf(sg))) + 0.001f;     // softplus + 1e-3

        const size_t r = rbase + q * TPB;
        outg[r]          = mu;
        outg[Bn * 8 + r] = sg;
        if (n == 0) outg[Bn * 16 + (r >> 3)] = vv;
    }
}

extern "C" void kernel_launch(void* const* d_in, const int* in_sizes, int n_in,
                              void* d_out, int out_size, void* d_ws, size_t ws_size,
                              hipStream_t stream) {
    const float* xg   = (const float*)d_in[0];
    const float* adjg = (const float*)d_in[1];
    const float* Wg   = (const float*)d_in[2];
    const float* ahg  = (const float*)d_in[3];
    const float* wog  = (const float*)d_in[4];
    const float* aog  = (const float*)d_in[5];
    const float* muW  = (const float*)d_in[6];
    const float* mub  = (const float*)d_in[7];
    const float* sgW  = (const float*)d_in[8];
    const float* sgb  = (const float*)d_in[9];
    const float* vW   = (const float*)d_in[10];
    const float* vb   = (const float*)d_in[11];
    float* outg = (float*)d_out;

    dim3 grid(Bn * 8 / (2 * TPB));  // 2048 blocks; 2 graph-rows per thread
    gat_ppo_kernel<<<grid, TPB, 0, stream>>>(xg, adjg, Wg, ahg, wog, aog,
                                             muW, mub, sgW, sgb, vW, vb, outg);
}

// Round 10
// 58.663 us; speedup vs baseline: 1.2165x; 1.2165x over previous
//
#include <hip/hip_runtime.h>
#include <math.h>

#define TPB 256

constexpr int Bn    = 131072;
constexpr float LOG2E = 1.4426950408889634f;

typedef float v2f __attribute__((ext_vector_type(2)));

__global__ __launch_bounds__(TPB)
void gat_ppo_kernel(const float* __restrict__ xg,
                    const float* __restrict__ adjg,
                    const float* __restrict__ Wg,
                    const float* __restrict__ ahg,
                    const float* __restrict__ wog,
                    const float* __restrict__ aog,
                    const float* __restrict__ muWg,
                    const float* __restrict__ mubg,
                    const float* __restrict__ sgWg,
                    const float* __restrict__ sgbg,
                    const float* __restrict__ vWg,
                    const float* __restrict__ vbg,
                    float* __restrict__ outg)
{
    // Two independent graph-rows per thread (q = 0,1), interleaved at
    // instruction level for 2x ILP. Per-head recompute of acc keeps the
    // tile read->write phases data-dependency-serialized (replay-safe in
    // round 8; round 9's dependency-free variant raced). No min-waves
    // launch_bounds hint: round 8's (256,4) forced 64 VGPR + scratch spill
    // (WRITE_SIZE 68MB). Block: 4 waves x 2 x 200 float4 = 25.6 KB LDS.
    __shared__ float4 tile[4 * 2 * 200];

    const int lb = threadIdx.x;
    const int w  = lb >> 6;                 // wave id in block
    const int g  = (lb & 63) >> 3;          // graph within wave (per tile)
    const int n  = lb & 7;                  // node id
    const size_t rbase = (size_t)blockIdx.x * (2 * TPB) + lb;

    float4* wtA = tile + w * 400;
    float4* wtB = wtA + 200;

    // ---- adj -> mask and x -> regs for both rows (independent chains) ----
    unsigned amask[2];
    float x[2][30];
    #pragma unroll
    for (int q = 0; q < 2; ++q) {
        const size_t r = rbase + q * TPB;
        const float4* a4 = (const float4*)(adjg) + r * 2;
        float4 a0 = a4[0], a1 = a4[1];
        amask[q] =  (unsigned)(a0.x > 0.0f)
                 | ((unsigned)(a0.y > 0.0f) << 1)
                 | ((unsigned)(a0.z > 0.0f) << 2)
                 | ((unsigned)(a0.w > 0.0f) << 3)
                 | ((unsigned)(a1.x > 0.0f) << 4)
                 | ((unsigned)(a1.y > 0.0f) << 5)
                 | ((unsigned)(a1.z > 0.0f) << 6)
                 | ((unsigned)(a1.w > 0.0f) << 7);
        const float2* xr = (const float2*)(xg + r * 30);
        #pragma unroll
        for (int k = 0; k < 15; ++k) {
            float2 v = xr[k];
            x[q][2 * k] = v.x; x[q][2 * k + 1] = v.y;
        }
    }

    // ---- per-head: Wh (both rows, shared W operand) -> tiles -> softmax -> agg ----
    const v2f* Wp = (const v2f*)Wg;
    float wh2[2] = {0.0f, 0.0f};

    #pragma unroll
    for (int h = 0; h < 3; ++h) {
        v2f acc[2][4];
        #pragma unroll
        for (int q = 0; q < 2; ++q)
            #pragma unroll
            for (int o2 = 0; o2 < 4; ++o2) acc[q][o2] = (v2f){0.0f, 0.0f};

        #pragma unroll
        for (int f = 0; f < 30; ++f) {
            #pragma unroll
            for (int o2 = 0; o2 < 4; ++o2) {
                v2f wv = Wp[h * 120 + f * 4 + o2];   // one s_load feeds both rows
                acc[0][o2] = __builtin_elementwise_fma((v2f){x[0][f], x[0][f]}, wv, acc[0][o2]);
                acc[1][o2] = __builtin_elementwise_fma((v2f){x[1][f], x[1][f]}, wv, acc[1][o2]);
            }
        }

        // scores (log2 domain) for both rows
        float f1h[2], f2h[2];
        #pragma unroll
        for (int q = 0; q < 2; ++q) {
            float s1 = 0.0f, s2 = 0.0f;
            #pragma unroll
            for (int o2 = 0; o2 < 4; ++o2) {
                s1 = fmaf(acc[q][o2].x, ahg[h * 16 + 2 * o2],     s1);
                s1 = fmaf(acc[q][o2].y, ahg[h * 16 + 2 * o2 + 1], s1);
                s2 = fmaf(acc[q][o2].x, ahg[h * 16 + 8 + 2 * o2],     s2);
                s2 = fmaf(acc[q][o2].y, ahg[h * 16 + 8 + 2 * o2 + 1], s2);
            }
            f1h[q] = s1 * LOG2E;
            f2h[q] = s2 * LOG2E;
        }

        // publish Wh rows to the two wave-local tiles
        wtA[g * 25 + n * 3]     = (float4){acc[0][0].x, acc[0][0].y, acc[0][1].x, acc[0][1].y};
        wtA[g * 25 + n * 3 + 1] = (float4){acc[0][2].x, acc[0][2].y, acc[0][3].x, acc[0][3].y};
        wtB[g * 25 + n * 3]     = (float4){acc[1][0].x, acc[1][0].y, acc[1][1].x, acc[1][1].y};
        wtB[g * 25 + n * 3 + 1] = (float4){acc[1][2].x, acc[1][2].y, acc[1][3].x, acc[1][3].y};

        // masked softmax weights (unnormalized, exp2), chains interleaved
        float p[2][8];
        float s[2] = {0.0f, 0.0f};
        #pragma unroll
        for (int m = 0; m < 8; ++m) {
            #pragma unroll
            for (int q = 0; q < 2; ++q) {
                float ev = f1h[q] + __shfl(f2h[q], m, 8);
                ev = fmaxf(ev, 0.2f * ev);                 // leaky (log2-scaled)
                float pe = ((amask[q] >> m) & 1u) ? __builtin_amdgcn_exp2f(ev) : 0.0f;
                p[q][m] = pe; s[q] += pe;
            }
        }

        // aggregate unnormalized (broadcast tile reads), interleaved
        v2f hacc[2][4];
        #pragma unroll
        for (int q = 0; q < 2; ++q)
            #pragma unroll
            for (int o2 = 0; o2 < 4; ++o2) hacc[q][o2] = (v2f){0.0f, 0.0f};

        #pragma unroll
        for (int m = 0; m < 8; ++m) {
            float4 loA = wtA[g * 25 + m * 3];
            float4 hiA = wtA[g * 25 + m * 3 + 1];
            float4 loB = wtB[g * 25 + m * 3];
            float4 hiB = wtB[g * 25 + m * 3 + 1];
            v2f avA = (v2f){p[0][m], p[0][m]};
            v2f avB = (v2f){p[1][m], p[1][m]};
            hacc[0][0] = __builtin_elementwise_fma(avA, (v2f){loA.x, loA.y}, hacc[0][0]);
            hacc[0][1] = __builtin_elementwise_fma(avA, (v2f){loA.z, loA.w}, hacc[0][1]);
            hacc[0][2] = __builtin_elementwise_fma(avA, (v2f){hiA.x, hiA.y}, hacc[0][2]);
            hacc[0][3] = __builtin_elementwise_fma(avA, (v2f){hiA.z, hiA.w}, hacc[0][3]);
            hacc[1][0] = __builtin_elementwise_fma(avB, (v2f){loB.x, loB.y}, hacc[1][0]);
            hacc[1][1] = __builtin_elementwise_fma(avB, (v2f){loB.z, loB.w}, hacc[1][1]);
            hacc[1][2] = __builtin_elementwise_fma(avB, (v2f){hiB.x, hiB.y}, hacc[1][2]);
            hacc[1][3] = __builtin_elementwise_fma(avB, (v2f){hiB.z, hiB.w}, hacc[1][3]);
        }

        #pragma unroll
        for (int q = 0; q < 2; ++q) {
            float rs = 1.0f / s[q];
            #pragma unroll
            for (int o2 = 0; o2 < 4; ++o2) {
                #pragma unroll
                for (int j = 0; j < 2; ++j) {
                    float hv = hacc[q][o2][j] * rs;
                    hv = (hv > 0.0f) ? hv : (__expf(hv) - 1.0f);       // elu
                    wh2[q] = fmaf(hv, wog[h * 8 + 2 * o2 + j], wh2[q]); // h @ W_out
                }
            }
        }
    }

    // ---- second GAT layer (log2 domain, deferred norm), both rows ----
    const float a0c = aog[0] * LOG2E, a1c = aog[1] * LOG2E;
    float g2v[2];
    #pragma unroll
    for (int q = 0; q < 2; ++q) {
        float wh2a[8];
        #pragma unroll
        for (int m = 0; m < 8; ++m) wh2a[m] = __shfl(wh2[q], m, 8);

        float g1 = a0c * wh2[q];
        float s2s = 0.0f, og = 0.0f;
        #pragma unroll
        for (int m = 0; m < 8; ++m) {
            float ev = fmaf(a1c, wh2a[m], g1);
            ev = fmaxf(ev, 0.2f * ev);
            float pe = ((amask[q] >> m) & 1u) ? __builtin_amdgcn_exp2f(ev) : 0.0f;
            s2s += pe;
            og = fmaf(pe, wh2a[m], og);
        }
        og /= s2s;
        g2v[q] = (og > 0.0f) ? og : (__expf(og) - 1.0f);   // elu -> g[b][n]
    }

    // ---- MLP heads for both rows ----
    const v2f* muWp = (const v2f*)muWg;
    const v2f* sgWp = (const v2f*)sgWg;
    const v2f* vWp  = (const v2f*)vWg;
    #pragma unroll
    for (int q = 0; q < 2; ++q) {
        v2f gp[4];
        #pragma unroll
        for (int m = 0; m < 4; ++m)
            gp[m] = (v2f){__shfl(g2v[q], 2 * m, 8), __shfl(g2v[q], 2 * m + 1, 8)};

        v2f ma = (v2f){0.0f, 0.0f}, sa = (v2f){0.0f, 0.0f}, va = (v2f){0.0f, 0.0f};
        #pragma unroll
        for (int k = 0; k < 4; ++k) {
            ma = __builtin_elementwise_fma(gp[k], muWp[n * 4 + k], ma);
            sa = __builtin_elementwise_fma(gp[k], sgWp[n * 4 + k], sa);
            va = __builtin_elementwise_fma(gp[k], vWp[k],          va);
        }
        float mu = ma.x + ma.y + mubg[n];
        float sg = sa.x + sa.y + sgbg[n];
        float vv = va.x + va.y + vbg[0];

        mu = 1.0f / (1.0f + __expf(-mu));                               // sigmoid
        sg = fmaxf(sg, 0.0f) + log1pf(__expf(-fabsf(sg))) + 0.001f;     // softplus + 1e-3

        const size_t r = rbase + q * TPB;
        outg[r]          = mu;
        outg[Bn * 8 + r] = sg;
        if (n == 0) outg[Bn * 16 + (r >> 3)] = vv;
    }
}

extern "C" void kernel_launch(void* const* d_in, const int* in_sizes, int n_in,
                              void* d_out, int out_size, void* d_ws, size_t ws_size,
                              hipStream_t stream) {
    const float* xg   = (const float*)d_in[0];
    const float* adjg = (const float*)d_in[1];
    const float* Wg   = (const float*)d_in[2];
    const float* ahg  = (const float*)d_in[3];
    const float* wog  = (const float*)d_in[4];
    const float* aog  = (const float*)d_in[5];
    const float* muW  = (const float*)d_in[6];
    const float* mub  = (const float*)d_in[7];
    const float* sgW  = (const float*)d_in[8];
    const float* sgb  = (const float*)d_in[9];
    const float* vW   = (const float*)d_in[10];
    const float* vb   = (const float*)d_in[11];
    float* outg = (float*)d_out;

    dim3 grid(Bn * 8 / (2 * TPB));  // 2048 blocks; 2 graph-rows per thread
    gat_ppo_kernel<<<grid, TPB, 0, stream>>>(xg, adjg, Wg, ahg, wog, aog,
                                             muW, mub, sgW, sgb, vW, vb, outg);
}

// Round 11
// 51.847 us; speedup vs baseline: 1.3765x; 1.1315x over previous
//
#include <hip/hip_runtime.h>
#include <math.h>

#define TPB 512

constexpr int Bn    = 131072;
constexpr float LOG2E = 1.4426950408889634f;

typedef float v2f __attribute__((ext_vector_type(2)));

__global__ __launch_bounds__(TPB)
void gat_ppo_kernel(const float* __restrict__ xg,
                    const float* __restrict__ adjg,
                    const float* __restrict__ Wg,
                    const float* __restrict__ ahg,
                    const float* __restrict__ wog,
                    const float* __restrict__ aog,
                    const float* __restrict__ muWg,
                    const float* __restrict__ mubg,
                    const float* __restrict__ sgWg,
                    const float* __restrict__ sgbg,
                    const float* __restrict__ vWg,
                    const float* __restrict__ vbg,
                    float* __restrict__ outg)
{
    // Round-5 structure (proven 50.4 us, replay-safe), block size doubled to
    // 512 threads = 8 waves. Hypothesis: in-flight workgroups/CU is the
    // occupancy quantum (~4 blocks observed), so waves/block is the lever.
    // Per-wave Wh tile: 8 graphs x 25 float4 -> 8 waves x 3.2 KB = 25.6 KB.
    __shared__ float4 tile[8 * 200];

    const int lb = threadIdx.x;
    const int w  = lb >> 6;                 // wave id in block (0..7)
    const int g  = (lb & 63) >> 3;          // graph within wave
    const int n  = lb & 7;                  // node id
    const size_t t = (size_t)blockIdx.x * TPB + lb;   // global row = b*8 + n

    float4* wt4 = tile + w * 200;

    // ---- adj row -> 8-bit mask ----
    unsigned amask;
    {
        const float4* a4 = (const float4*)(adjg) + t * 2;
        float4 a0 = a4[0], a1 = a4[1];
        amask =  (unsigned)(a0.x > 0.0f)
              | ((unsigned)(a0.y > 0.0f) << 1)
              | ((unsigned)(a0.z > 0.0f) << 2)
              | ((unsigned)(a0.w > 0.0f) << 3)
              | ((unsigned)(a1.x > 0.0f) << 4)
              | ((unsigned)(a1.y > 0.0f) << 5)
              | ((unsigned)(a1.z > 0.0f) << 6)
              | ((unsigned)(a1.w > 0.0f) << 7);
    }

    // ---- x row: direct per-lane loads (L1/L2-served, proven in R5) ----
    float x[30];
    {
        const float2* xr = (const float2*)(xg + t * 30);
        #pragma unroll
        for (int k = 0; k < 15; ++k) {
            float2 v = xr[k];
            x[2 * k] = v.x; x[2 * k + 1] = v.y;
        }
    }

    // ---- per-head: Wh row (pk-FMA) -> LDS tile -> softmax -> aggregate ----
    const v2f* Wp = (const v2f*)Wg;
    float wh2 = 0.0f;

    #pragma unroll
    for (int h = 0; h < 3; ++h) {
        v2f acc[4];
        #pragma unroll
        for (int o2 = 0; o2 < 4; ++o2) acc[o2] = (v2f){0.0f, 0.0f};
        #pragma unroll
        for (int f = 0; f < 30; ++f) {
            v2f xf = (v2f){x[f], x[f]};
            #pragma unroll
            for (int o2 = 0; o2 < 4; ++o2)
                acc[o2] = __builtin_elementwise_fma(xf, Wp[h * 120 + f * 4 + o2], acc[o2]);
        }

        // f1, f2 scores (log2 domain)
        float s1 = 0.0f, s2 = 0.0f;
        #pragma unroll
        for (int o2 = 0; o2 < 4; ++o2) {
            s1 = fmaf(acc[o2].x, ahg[h * 16 + 2 * o2],     s1);
            s1 = fmaf(acc[o2].y, ahg[h * 16 + 2 * o2 + 1], s1);
            s2 = fmaf(acc[o2].x, ahg[h * 16 + 8 + 2 * o2],     s2);
            s2 = fmaf(acc[o2].y, ahg[h * 16 + 8 + 2 * o2 + 1], s2);
        }
        float f1h = s1 * LOG2E;
        float f2h = s2 * LOG2E;

        // publish own Wh row to the wave-local tile (2 x b128)
        wt4[g * 25 + n * 3]     = (float4){acc[0].x, acc[0].y, acc[1].x, acc[1].y};
        wt4[g * 25 + n * 3 + 1] = (float4){acc[2].x, acc[2].y, acc[3].x, acc[3].y};

        // masked softmax weights, unnormalized (no max pass, exp2)
        float p[8];
        float s = 0.0f;
        #pragma unroll
        for (int m = 0; m < 8; ++m) {
            float ev = f1h + __shfl(f2h, m, 8);
            ev = fmaxf(ev, 0.2f * ev);                    // leaky (log2-scaled)
            float pe = ((amask >> m) & 1u) ? __builtin_amdgcn_exp2f(ev) : 0.0f;
            p[m] = pe; s += pe;
        }

        // aggregate unnormalized; divide once at the end
        v2f hacc[4];
        #pragma unroll
        for (int o2 = 0; o2 < 4; ++o2) hacc[o2] = (v2f){0.0f, 0.0f};
        #pragma unroll
        for (int m = 0; m < 8; ++m) {
            float4 lo = wt4[g * 25 + m * 3];
            float4 hi = wt4[g * 25 + m * 3 + 1];
            v2f av = (v2f){p[m], p[m]};
            hacc[0] = __builtin_elementwise_fma(av, (v2f){lo.x, lo.y}, hacc[0]);
            hacc[1] = __builtin_elementwise_fma(av, (v2f){lo.z, lo.w}, hacc[1]);
            hacc[2] = __builtin_elementwise_fma(av, (v2f){hi.x, hi.y}, hacc[2]);
            hacc[3] = __builtin_elementwise_fma(av, (v2f){hi.z, hi.w}, hacc[3]);
        }
        float rs = 1.0f / s;
        #pragma unroll
        for (int o2 = 0; o2 < 4; ++o2) {
            #pragma unroll
            for (int j = 0; j < 2; ++j) {
                float hv = hacc[o2][j] * rs;
                hv = (hv > 0.0f) ? hv : (__expf(hv) - 1.0f);   // elu
                wh2 = fmaf(hv, wog[h * 8 + 2 * o2 + j], wh2);  // h @ W_out
            }
        }
    }

    // ---- second GAT layer on Wh2 (log2 domain, no max pass, deferred norm) ----
    const float a0c = aog[0] * LOG2E, a1c = aog[1] * LOG2E;
    float wh2a[8];
    #pragma unroll
    for (int m = 0; m < 8; ++m) wh2a[m] = __shfl(wh2, m, 8);

    float g1 = a0c * wh2;
    float s2s = 0.0f;
    float og = 0.0f;
    #pragma unroll
    for (int m = 0; m < 8; ++m) {
        float ev = fmaf(a1c, wh2a[m], g1);
        ev = fmaxf(ev, 0.2f * ev);
        float pe = ((amask >> m) & 1u) ? __builtin_amdgcn_exp2f(ev) : 0.0f;
        s2s += pe;
        og = fmaf(pe, wh2a[m], og);
    }
    og /= s2s;
    float g2v = (og > 0.0f) ? og : (__expf(og) - 1.0f);   // elu -> g[b][n]

    // ---- MLP heads: mu, sigma (per node), value (per batch) ----
    v2f gp[4];
    #pragma unroll
    for (int m = 0; m < 4; ++m)
        gp[m] = (v2f){__shfl(g2v, 2 * m, 8), __shfl(g2v, 2 * m + 1, 8)};

    const v2f* muWp = (const v2f*)muWg;
    const v2f* sgWp = (const v2f*)sgWg;
    const v2f* vWp  = (const v2f*)vWg;
    v2f ma = (v2f){0.0f, 0.0f}, sa = (v2f){0.0f, 0.0f}, va = (v2f){0.0f, 0.0f};
    #pragma unroll
    for (int k = 0; k < 4; ++k) {
        ma = __builtin_elementwise_fma(gp[k], muWp[n * 4 + k], ma);
        sa = __builtin_elementwise_fma(gp[k], sgWp[n * 4 + k], sa);
        va = __builtin_elementwise_fma(gp[k], vWp[k],          va);
    }
    float mu = ma.x + ma.y + mubg[n];
    float sg = sa.x + sa.y + sgbg[n];
    float vv = va.x + va.y + vbg[0];

    mu = 1.0f / (1.0f + __expf(-mu));                               // sigmoid
    sg = fmaxf(sg, 0.0f) + log1pf(__expf(-fabsf(sg))) + 0.001f;     // softplus + 1e-3

    outg[t]          = mu;
    outg[Bn * 8 + t] = sg;
    if (n == 0) outg[Bn * 16 + (t >> 3)] = vv;
}

extern "C" void kernel_launch(void* const* d_in, const int* in_sizes, int n_in,
                              void* d_out, int out_size, void* d_ws, size_t ws_size,
                              hipStream_t stream) {
    const float* xg   = (const float*)d_in[0];
    const float* adjg = (const float*)d_in[1];
    const float* Wg   = (const float*)d_in[2];
    const float* ahg  = (const float*)d_in[3];
    const float* wog  = (const float*)d_in[4];
    const float* aog  = (const float*)d_in[5];
    const float* muW  = (const float*)d_in[6];
    const float* mub  = (const float*)d_in[7];
    const float* sgW  = (const float*)d_in[8];
    const float* sgb  = (const float*)d_in[9];
    const float* vW   = (const float*)d_in[10];
    const float* vb   = (const float*)d_in[11];
    float* outg = (float*)d_out;

    dim3 grid(Bn * 8 / TPB);  // 2048 blocks of 512 threads (8 waves/block)
    gat_ppo_kernel<<<grid, TPB, 0, stream>>>(xg, adjg, Wg, ahg, wog, aog,
                                             muW, mub, sgW, sgb, vW, vb, outg);
}

// Round 12
// 49.085 us; speedup vs baseline: 1.4539x; 1.0563x over previous
//
#include <hip/hip_runtime.h>
#include <math.h>

#define TPB 256

constexpr int Bn    = 131072;
constexpr float LOG2E = 1.4426950408889634f;

typedef float v2f __attribute__((ext_vector_type(2)));

__global__ __launch_bounds__(TPB)
void gat_ppo_kernel(const float* __restrict__ xg,
                    const float* __restrict__ adjg,
                    const float* __restrict__ Wg,
                    const float* __restrict__ ahg,
                    const float* __restrict__ wog,
                    const float* __restrict__ aog,
                    const float* __restrict__ muWg,
                    const float* __restrict__ mubg,
                    const float* __restrict__ sgWg,
                    const float* __restrict__ sgbg,
                    const float* __restrict__ vWg,
                    const float* __restrict__ vbg,
                    float* __restrict__ outg)
{
    // Merged f-pass + 3 CONCURRENT head phases. Each wave owns 3 head-tiles
    // (8 graphs x 25 float4 each): 4 waves x 3 x 200 float4 = 38.4 KB/block.
    // A compiler memory fence separates tile writes from tile reads: the
    // cross-lane write->read dependency is invisible to alias analysis
    // (round-9 race mechanism), so we pin program order explicitly; the
    // per-wave in-order LDS pipe guarantees the hardware side.
    __shared__ float4 tile[4][3][200];

    const int lb = threadIdx.x;
    const int w  = lb >> 6;                 // wave id in block
    const int g  = (lb & 63) >> 3;          // graph within wave
    const int n  = lb & 7;                  // node id
    const size_t t = (size_t)blockIdx.x * TPB + lb;   // global row = b*8 + n

    // ---- adj row -> 8-bit mask ----
    unsigned amask;
    {
        const float4* a4 = (const float4*)(adjg) + t * 2;
        float4 a0 = a4[0], a1 = a4[1];
        amask =  (unsigned)(a0.x > 0.0f)
              | ((unsigned)(a0.y > 0.0f) << 1)
              | ((unsigned)(a0.z > 0.0f) << 2)
              | ((unsigned)(a0.w > 0.0f) << 3)
              | ((unsigned)(a1.x > 0.0f) << 4)
              | ((unsigned)(a1.y > 0.0f) << 5)
              | ((unsigned)(a1.z > 0.0f) << 6)
              | ((unsigned)(a1.w > 0.0f) << 7);
    }

    // ---- merged f-pass: all 3 heads' Wh accumulators in one x stream ----
    const v2f* Wp = (const v2f*)Wg;
    v2f acc[3][4];
    #pragma unroll
    for (int h = 0; h < 3; ++h)
        #pragma unroll
        for (int o2 = 0; o2 < 4; ++o2) acc[h][o2] = (v2f){0.0f, 0.0f};

    {
        const float2* xr = (const float2*)(xg + t * 30);
        #pragma unroll
        for (int k = 0; k < 15; ++k) {
            float2 v = xr[k];
            #pragma unroll
            for (int e = 0; e < 2; ++e) {
                const int f = 2 * k + e;
                const float xf = e ? v.y : v.x;
                v2f xv = (v2f){xf, xf};
                #pragma unroll
                for (int h = 0; h < 3; ++h)
                    #pragma unroll
                    for (int o2 = 0; o2 < 4; ++o2)
                        acc[h][o2] = __builtin_elementwise_fma(xv, Wp[h * 120 + f * 4 + o2], acc[h][o2]);
            }
        }
    }

    // ---- scores for all heads (log2 domain) ----
    float f1h[3], f2h[3];
    #pragma unroll
    for (int h = 0; h < 3; ++h) {
        float s1 = 0.0f, s2 = 0.0f;
        #pragma unroll
        for (int o2 = 0; o2 < 4; ++o2) {
            s1 = fmaf(acc[h][o2].x, ahg[h * 16 + 2 * o2],     s1);
            s1 = fmaf(acc[h][o2].y, ahg[h * 16 + 2 * o2 + 1], s1);
            s2 = fmaf(acc[h][o2].x, ahg[h * 16 + 8 + 2 * o2],     s2);
            s2 = fmaf(acc[h][o2].y, ahg[h * 16 + 8 + 2 * o2 + 1], s2);
        }
        f1h[h] = s1 * LOG2E;
        f2h[h] = s2 * LOG2E;
    }

    // ---- publish all 3 heads' Wh rows (6 x ds_write_b128) ----
    #pragma unroll
    for (int h = 0; h < 3; ++h) {
        tile[w][h][g * 25 + n * 3]     = (float4){acc[h][0].x, acc[h][0].y, acc[h][1].x, acc[h][1].y};
        tile[w][h][g * 25 + n * 3 + 1] = (float4){acc[h][2].x, acc[h][2].y, acc[h][3].x, acc[h][3].y};
    }
    // Compiler fence: tile reads below must not hoist above the writes
    // (cross-lane dependency invisible to alias analysis). HW: per-wave
    // in-order LDS pipe makes write->read safe once order is pinned.
    asm volatile("" ::: "memory");
    __builtin_amdgcn_sched_barrier(0);

    // ---- 3 softmaxes interleaved (24 independent shfl + exp chains) ----
    float p[3][8];
    float s[3] = {0.0f, 0.0f, 0.0f};
    #pragma unroll
    for (int m = 0; m < 8; ++m) {
        const bool on = (amask >> m) & 1u;
        #pragma unroll
        for (int h = 0; h < 3; ++h) {
            float ev = f1h[h] + __shfl(f2h[h], m, 8);
            ev = fmaxf(ev, 0.2f * ev);                 // leaky (log2-scaled)
            float pe = on ? __builtin_amdgcn_exp2f(ev) : 0.0f;
            p[h][m] = pe; s[h] += pe;
        }
    }

    // ---- 3 aggregations: 48 independent broadcast b128 reads ----
    v2f hacc[3][4];
    #pragma unroll
    for (int h = 0; h < 3; ++h)
        #pragma unroll
        for (int o2 = 0; o2 < 4; ++o2) hacc[h][o2] = (v2f){0.0f, 0.0f};

    #pragma unroll
    for (int m = 0; m < 8; ++m) {
        #pragma unroll
        for (int h = 0; h < 3; ++h) {
            float4 lo = tile[w][h][g * 25 + m * 3];
            float4 hi = tile[w][h][g * 25 + m * 3 + 1];
            v2f av = (v2f){p[h][m], p[h][m]};
            hacc[h][0] = __builtin_elementwise_fma(av, (v2f){lo.x, lo.y}, hacc[h][0]);
            hacc[h][1] = __builtin_elementwise_fma(av, (v2f){lo.z, lo.w}, hacc[h][1]);
            hacc[h][2] = __builtin_elementwise_fma(av, (v2f){hi.x, hi.y}, hacc[h][2]);
            hacc[h][3] = __builtin_elementwise_fma(av, (v2f){hi.z, hi.w}, hacc[h][3]);
        }
    }

    // ---- elu + W_out fold ----
    float wh2 = 0.0f;
    #pragma unroll
    for (int h = 0; h < 3; ++h) {
        float rs = 1.0f / s[h];
        #pragma unroll
        for (int o2 = 0; o2 < 4; ++o2) {
            #pragma unroll
            for (int j = 0; j < 2; ++j) {
                float hv = hacc[h][o2][j] * rs;
                hv = (hv > 0.0f) ? hv : (__expf(hv) - 1.0f);   // elu
                wh2 = fmaf(hv, wog[h * 8 + 2 * o2 + j], wh2);  // h @ W_out
            }
        }
    }

    // ---- second GAT layer on Wh2 (log2 domain, deferred norm) ----
    const float a0c = aog[0] * LOG2E, a1c = aog[1] * LOG2E;
    float wh2a[8];
    #pragma unroll
    for (int m = 0; m < 8; ++m) wh2a[m] = __shfl(wh2, m, 8);

    float g1 = a0c * wh2;
    float s2s = 0.0f;
    float og = 0.0f;
    #pragma unroll
    for (int m = 0; m < 8; ++m) {
        float ev = fmaf(a1c, wh2a[m], g1);
        ev = fmaxf(ev, 0.2f * ev);
        float pe = ((amask >> m) & 1u) ? __builtin_amdgcn_exp2f(ev) : 0.0f;
        s2s += pe;
        og = fmaf(pe, wh2a[m], og);
    }
    og /= s2s;
    float g2v = (og > 0.0f) ? og : (__expf(og) - 1.0f);   // elu -> g[b][n]

    // ---- MLP heads: mu, sigma (per node), value (per batch) ----
    v2f gp[4];
    #pragma unroll
    for (int m = 0; m < 4; ++m)
        gp[m] = (v2f){__shfl(g2v, 2 * m, 8), __shfl(g2v, 2 * m + 1, 8)};

    const v2f* muWp = (const v2f*)muWg;
    const v2f* sgWp = (const v2f*)sgWg;
    const v2f* vWp  = (const v2f*)vWg;
    v2f ma = (v2f){0.0f, 0.0f}, sa = (v2f){0.0f, 0.0f}, va = (v2f){0.0f, 0.0f};
    #pragma unroll
    for (int k = 0; k < 4; ++k) {
        ma = __builtin_elementwise_fma(gp[k], muWp[n * 4 + k], ma);
        sa = __builtin_elementwise_fma(gp[k], sgWp[n * 4 + k], sa);
        va = __builtin_elementwise_fma(gp[k], vWp[k],          va);
    }
    float mu = ma.x + ma.y + mubg[n];
    float sg = sa.x + sa.y + sgbg[n];
    float vv = va.x + va.y + vbg[0];

    mu = 1.0f / (1.0f + __expf(-mu));                               // sigmoid
    sg = fmaxf(sg, 0.0f) + log1pf(__expf(-fabsf(sg))) + 0.001f;     // softplus + 1e-3

    outg[t]          = mu;
    outg[Bn * 8 + t] = sg;
    if (n == 0) outg[Bn * 16 + (t >> 3)] = vv;
}

extern "C" void kernel_launch(void* const* d_in, const int* in_sizes, int n_in,
                              void* d_out, int out_size, void* d_ws, size_t ws_size,
                              hipStream_t stream) {
    const float* xg   = (const float*)d_in[0];
    const float* adjg = (const float*)d_in[1];
    const float* Wg   = (const float*)d_in[2];
    const float* ahg  = (const float*)d_in[3];
    const float* wog  = (const float*)d_in[4];
    const float* aog  = (const float*)d_in[5];
    const float* muW  = (const float*)d_in[6];
    const float* mub  = (const float*)d_in[7];
    const float* sgW  = (const float*)d_in[8];
    const float* sgb  = (const float*)d_in[9];
    const float* vW   = (const float*)d_in[10];
    const float* vb   = (const float*)d_in[11];
    float* outg = (float*)d_out;

    dim3 grid(Bn * 8 / TPB);  // 4096 blocks of 256 threads; 8 lanes per graph
    gat_ppo_kernel<<<grid, TPB, 0, stream>>>(xg, adjg, Wg, ahg, wog, aog,
                                             muW, mub, sgW, sgb, vW, vb, outg);
}